// Round 11
// baseline (205.379 us; speedup 1.0000x reference)
//
#include <hip/hip_runtime.h>
#include <math.h>

// Negative L1 cdist: out[n,m] = -sum_d |x[n,d] - w[m,d]|
// N=8192, M=1024, D=64, fp32 in/out.
//
// Session rate table (measured): f32 sub/sub-abs = 4 cy/elem (full rate);
// v_sad_u8 ~4.25; v_sad_u16 ~8; v_pk_f16/fdot2 ~8-12 (R9/R10: f16 path 39-44us
// vs 11.6 model -> sub-rate/scalarized). Plain f32 is the fastest mix AND
// exact AND needs no quant kernel.
// R11: R8's proven issue-bound structure with f32 math:
//   - lane <-> m (1 col/lane): coalesced 1KB/wave stores
//   - w row = wq[64] flat f32 array (simple load preamble -> stays in VGPRs;
//     R9's AGPR pathology came with cvt-heavy preambles, R8's flat load was fine)
//   - x tile (16 rows, 4KB) staged once, broadcast ds_read_b128, one barrier
//   - 4 independent acc chains; single kernel, no workspace
// Floor: 2 VALU/elem = 32.8k cy/SIMD = 13.7 us chip-wide.

constexpr int Nn = 8192, Mm = 1024, Dd = 64;
constexpr int NR = 16;                     // n-rows per block

__global__ __launch_bounds__(256, 4) void cdist_l1_f32_kernel(
    const float* __restrict__ x, const float* __restrict__ w,
    float* __restrict__ out)
{
    __shared__ float4 sx4[NR * 16];        // 16 rows x 64 f32 = 4 KB
    const int t  = threadIdx.x;
    const int m  = blockIdx.x * 256 + t;   // lane <-> m column
    const int n0 = blockIdx.y * NR;

    // ---- stage x tile: 256 float4 = 16 rows, fully coalesced ----
    sx4[t] = ((const float4*)(x + (size_t)n0 * Dd))[t];

    // ---- w row -> 64 f32 in VGPRs (flat array, minimal temps) ----
    float wq[Dd];
    {
        const float4* wp = (const float4*)(w + (size_t)m * Dd);
#pragma unroll
        for (int i = 0; i < 16; ++i) {
            const float4 v = wp[i];
            wq[4 * i + 0] = v.x;
            wq[4 * i + 1] = v.y;
            wq[4 * i + 2] = v.z;
            wq[4 * i + 3] = v.w;
        }
    }
    __syncthreads();                       // the only barrier

    for (int i = 0; i < NR; ++i) {
        const float4* xr = &sx4[i * 16];   // 16x ds_read_b128, broadcast
        float a0 = 0.0f, a1 = 0.0f, a2 = 0.0f, a3 = 0.0f;
#pragma unroll
        for (int j = 0; j < 16; ++j) {
            const float4 xv = xr[j];
            // v_sub_f32 + v_sub_f32 with |src1| modifier: 2 VALU per elem
            a0 -= fabsf(xv.x - wq[4 * j + 0]);
            a1 -= fabsf(xv.y - wq[4 * j + 1]);
            a2 -= fabsf(xv.z - wq[4 * j + 2]);
            a3 -= fabsf(xv.w - wq[4 * j + 3]);
        }
        // coalesced: 1 KB contiguous per wave-row
        out[(size_t)(n0 + i) * Mm + m] = (a0 + a1) + (a2 + a3);
    }
}

extern "C" void kernel_launch(void* const* d_in, const int* in_sizes, int n_in,
                              void* d_out, int out_size, void* d_ws, size_t ws_size,
                              hipStream_t stream) {
    (void)in_sizes; (void)n_in; (void)out_size; (void)d_ws; (void)ws_size;
    const float* x = (const float*)d_in[0];   // [8192, 64] fp32
    const float* w = (const float*)d_in[1];   // [1024, 64] fp32
    float* out = (float*)d_out;               // [8192, 1024] fp32

    // (4, 512) = 2048 blocks; 4 blocks/CU resident (VGPR-capped), 2 passes
    cdist_l1_f32_kernel<<<dim3(Mm / 256, Nn / NR), dim3(256), 0, stream>>>(
        x, w, out);
}